// Round 7
// baseline (566.926 us; speedup 1.0000x reference)
//
#include <hip/hip_runtime.h>

// Nearest-centroid assignment. out[0..N) = max_sim (float), out[N..2N) = argmax (as float).
//
// Decision semantics = round-6 validated np bit-model (einsum baseline-SSE3 unfused
// cascade + AVX512F pairwise norms + fl32 chain + first-max). Fast path: f16x3-split
// MFMA GEMM (hi*hi + hi*lo + lo*hi, fp32 accum), |fast - np| ~ 1e-4 << EPS/2.
// v6: PIN register budget with amdgpu_waves_per_eu(2,2). v3-v5 reported VGPR=128 with
// ~8.2 MB/dispatch scratch writes: launch_bounds(256,2) is only a MINIMUM, so the
// allocator targeted 4 waves/EU (128 regs) and spilled the ~226-reg live set into the
// K-loop. Pinning 2 waves/EU gives the 256-reg budget the design was built for:
// A-fragments truly register-resident, no scratch in the loop, sound vmcnt counting.
// Quad-buffered LDS B tiles, prefetch depth 2 (counted vmcnt(8)), one barrier/stage,
// per-block rotated stage schedule (kept from v5; harmless).
// Margin >= EPS -> winner provably = np winner, recompute np-bit-exactly;
// margin < EPS -> row -> fallback (full np-exact).
constexpr int N = 131072;
constexpr int D = 256;
constexpr int K = 1024;

constexpr int TM = 128;   // rows per block
constexpr int TK = 128;   // centroids per chunk
constexpr float EPS = 0.08f;

typedef _Float16 f16x8 __attribute__((ext_vector_type(8)));
typedef float f32x4 __attribute__((ext_vector_type(4)));

// c pre-split into fragment-tiled layout: [stage=kblk*8+dc][part][kg][krow][e]
// stage block = 8192 f16 (16 KiB); 64 real stages + 2 pad stages (uniform prefetch).
__device__ _Float16 g_ctile[66 * 8192];

__device__ __forceinline__ float sqf(float a) { return __fmul_rn(a, a); }

// numpy AVX512F pairwise base case over 128 contiguous squares.
__device__ __forceinline__ float np_sumsq128(const float* q) {
    float lane[16];
#pragma unroll
    for (int j = 0; j < 16; j++) {
        const float r0 = __fadd_rn(sqf(q[j]),      sqf(q[64 + j]));
        const float r1 = __fadd_rn(sqf(q[16 + j]), sqf(q[80 + j]));
        const float r2 = __fadd_rn(sqf(q[32 + j]), sqf(q[96 + j]));
        const float r3 = __fadd_rn(sqf(q[48 + j]), sqf(q[112 + j]));
        lane[j] = __fadd_rn(__fadd_rn(r0, r1), __fadd_rn(r2, r3));
    }
    float t[8];
#pragma unroll
    for (int i = 0; i < 8; i++) t[i] = __fadd_rn(lane[i], lane[i + 8]);
    float u[4];
#pragma unroll
    for (int i = 0; i < 4; i++) u[i] = __fadd_rn(t[i], t[i + 4]);
    return __fadd_rn(__fadd_rn(u[0], u[2]), __fadd_rn(u[1], u[3]));
}
__device__ __forceinline__ float np_pw256_sq(const float* p) {
    return __fadd_rn(np_sumsq128(p), np_sumsq128(p + 128));
}

// np einsum bit-exact dot over 256 contiguous floats.
__device__ __forceinline__ float np_dot256(const float* a, const float* b) {
    float A[4] = {0.f, 0.f, 0.f, 0.f};
#pragma unroll 4
    for (int t = 0; t < 16; t++) {
#pragma unroll
        for (int i = 3; i >= 0; i--) {
            const int base = 16 * t + 4 * i;
#pragma unroll
            for (int j = 0; j < 4; j++)
                A[j] = __fadd_rn(A[j], __fmul_rn(a[base + j], b[base + j]));
        }
    }
    return __fadd_rn(__fadd_rn(A[0], A[1]), __fadd_rn(A[2], A[3]));
}

// split one float component into (hi,lo) f16 pair at index idx of vectors he/le
#define SPL(vec, comp, he, le, idx)                                  \
    {                                                                \
        const float fv_ = (vec).comp;                                \
        const _Float16 hh_ = (_Float16)fv_;                          \
        he[idx] = hh_;                                               \
        le[idx] = (_Float16)(fv_ - (float)hh_);                      \
    }

// Pre-split c into g_ctile fragment-tiled layout; threads with idx<K also compute cn.
__global__ __launch_bounds__(256) void prep_kernel(const float* __restrict__ c,
                                                   float* __restrict__ cn) {
    const int idx = blockIdx.x * 256 + threadIdx.x;   // [0, 32768)
    const int kglob = idx >> 5;                        // centroid row
    const int dslot = idx & 31;                        // dc*4 + kg
    const int dc = dslot >> 2, kg = dslot & 3;
    const float* src = c + (size_t)kglob * D + dc * 32 + kg * 8;
    const float4 s0 = ((const float4*)src)[0];
    const float4 s1 = ((const float4*)src)[1];
    f16x8 h, l;
    SPL(s0, x, h, l, 0) SPL(s0, y, h, l, 1) SPL(s0, z, h, l, 2) SPL(s0, w, h, l, 3)
    SPL(s1, x, h, l, 4) SPL(s1, y, h, l, 5) SPL(s1, z, h, l, 6) SPL(s1, w, h, l, 7)
    const int kblk = kglob >> 7, krow = kglob & 127;
    const int st = kblk * 8 + dc;
    _Float16* base = g_ctile + (size_t)st * 8192;
    *(f16x8*)&base[kg * 1024 + krow * 8]        = h;
    *(f16x8*)&base[4096 + kg * 1024 + krow * 8] = l;
    if (idx < K) cn[idx] = np_pw256_sq(c + (size_t)idx * D);
}

#define WAITVM(n) asm volatile("s_waitcnt vmcnt(" #n ")" ::: "memory")

__global__ __launch_bounds__(256)
__attribute__((amdgpu_waves_per_eu(2, 2)))
void fast_kernel(const float* __restrict__ x,
                 const float* __restrict__ c,
                 const float* __restrict__ cn,
                 float* __restrict__ out,
                 int* __restrict__ cnt,
                 int* __restrict__ list) {
    __shared__ _Float16 cs[4][8192] __attribute__((aligned(16)));  // quad-buffered B tile
    __shared__ float cn_sh[K];
    __shared__ float xn_sh[TM];
    __shared__ int   rbi[TM];
    __shared__ int   rok[TM];

    const int t    = threadIdx.x;
    const int n0   = blockIdx.x * TM;
    const int lane = t & 63;
    const int w    = t >> 6;        // wave id 0..3
    const int wrow = w * 32;        // wave owns rows [wrow, wrow+32)
    const int lr   = lane & 15;     // fragment row/col coordinate
    const int lg   = lane >> 4;     // fragment k-group / C row-group

    // per-block schedule rotation (de-correlates g_ctile broadcast across blocks)
    const int kbR = blockIdx.x & 7;
    const int dcR = (blockIdx.x >> 3) & 7;
    // physical stage for linear exec position p (p in [0,64); >=64 -> pad stage)
#define PHYS(p_) ((p_) < 64 ? (((((p_) >> 3) + kbR) & 7) << 3) | ((((p_) & 7) + dcR) & 7) : (p_))

#define STAGE(buf_, sidx_)                                                          \
    {                                                                               \
        const _Float16* gp_ = g_ctile + (size_t)(sidx_) * 8192 + t * 8;             \
        _Float16* lp_ = &cs[buf_][t * 8];                                           \
        _Pragma("unroll")                                                           \
        for (int u_ = 0; u_ < 4; u_++)                                              \
            __builtin_amdgcn_global_load_lds(                                       \
                (const __attribute__((address_space(1))) void*)(gp_ + u_ * 2048),   \
                (__attribute__((address_space(3))) void*)(lp_ + u_ * 2048),         \
                16, 0, 0);                                                          \
    }

    // issue first two stages (rotated), then overlap prologue work with the DMA
    STAGE(0, PHYS(0));
    STAGE(1, PHYS(1));

#pragma unroll
    for (int q = 0; q < 4; q++) cn_sh[t + 256 * q] = cn[t + 256 * q];
    if (t < TM) xn_sh[t] = np_pw256_sq(x + (size_t)(n0 + t) * D);

    // A fragments: load + hi/lo split ONCE into registers, PRE-ROTATED so that
    // execution index st (static) holds physical depth (st + dcR) & 7.
    // ah/al[i][st] covers row (wrow + 16*i + lr), d = ((st+dcR)&7)*32 + lg*8 .. +8
    f16x8 ah[2][8], al[2][8];
#pragma unroll
    for (int st = 0; st < 8; st++) {
        const int pst = (st + dcR) & 7;   // physical depth stage
#pragma unroll
        for (int i = 0; i < 2; i++) {
            const float* src = x + (size_t)(n0 + wrow + 16 * i + lr) * D + pst * 32 + lg * 8;
            const float4 s0 = ((const float4*)src)[0];
            const float4 s1 = ((const float4*)src)[1];
            f16x8 h, l;
            SPL(s0, x, h, l, 0) SPL(s0, y, h, l, 1) SPL(s0, z, h, l, 2) SPL(s0, w, h, l, 3)
            SPL(s1, x, h, l, 4) SPL(s1, y, h, l, 5) SPL(s1, z, h, l, 6) SPL(s1, w, h, l, 7)
            ah[i][st] = h; al[i][st] = l;
        }
    }

    float v1[8], v2[8];
    int   i1[8];
#pragma unroll
    for (int s = 0; s < 8; s++) {
        v1[s] = -__builtin_inff(); v2[s] = -__builtin_inff(); i1[s] = 0;
    }

    __syncthreads();   // xn/cn visible; also drains stages 0,1 (vmcnt 0)

    for (int kb0 = 0; kb0 < 8; kb0++) {
        const int kbE = (kb0 + kbR) & 7;   // physical kb chunk this iteration computes
        f32x4 acc[2][8];
#pragma unroll
        for (int i = 0; i < 2; i++)
#pragma unroll
            for (int j = 0; j < 8; j++) acc[i][j] = (f32x4)(0.f);

#pragma unroll
        for (int dc8 = 0; dc8 < 8; dc8++) {
            // linear exec position p = kb0*8 + dc8; buffer ids p&3 == dc8&3 (static)
            const int p2 = kb0 * 8 + dc8 + 2;
            STAGE((dc8 + 2) & 3, PHYS(p2));       // pad stages 64,65 land in dead buffers
            WAITVM(8);                            // oldest stage (p) complete
            __builtin_amdgcn_s_barrier();         // all waves' portions of stage p in LDS
            __builtin_amdgcn_sched_barrier(0);    // no ds_read hoisting above barrier
            asm volatile("" ::: "memory");

            const _Float16* csb = &cs[dc8 & 3][0];
            __builtin_amdgcn_s_setprio(1);
#pragma unroll
            for (int j = 0; j < 8; j++) {
                const f16x8 bh = *(const f16x8*)&csb[lg * 1024 + (16 * j + lr) * 8];
                const f16x8 bl = *(const f16x8*)&csb[4096 + lg * 1024 + (16 * j + lr) * 8];
                acc[0][j] = __builtin_amdgcn_mfma_f32_16x16x32_f16(ah[0][dc8], bh, acc[0][j], 0, 0, 0);
                acc[1][j] = __builtin_amdgcn_mfma_f32_16x16x32_f16(ah[1][dc8], bh, acc[1][j], 0, 0, 0);
                acc[0][j] = __builtin_amdgcn_mfma_f32_16x16x32_f16(al[0][dc8], bh, acc[0][j], 0, 0, 0);
                acc[1][j] = __builtin_amdgcn_mfma_f32_16x16x32_f16(al[1][dc8], bh, acc[1][j], 0, 0, 0);
                acc[0][j] = __builtin_amdgcn_mfma_f32_16x16x32_f16(ah[0][dc8], bl, acc[0][j], 0, 0, 0);
                acc[1][j] = __builtin_amdgcn_mfma_f32_16x16x32_f16(ah[1][dc8], bl, acc[1][j], 0, 0, 0);
            }
            __builtin_amdgcn_s_setprio(0);
            asm volatile("" ::: "memory");
            // no trailing barrier: 4-buffer rotation keeps issue(p+2) != any live read buffer
        }

        // chunk epilogue: C/D layout col = lane&15, row = 4*(lane>>4)+reg (m89-verified).
        // kg ascending within lane (j ascending); first-max kept via strict >.
        // (kb rotation is safe: distinct values are order-independent; exact ties
        //  force margin 0 -> fallback, so tie-index order never reaches the output.)
#pragma unroll
        for (int j = 0; j < 8; j++) {
            const int kg_ = kbE * TK + 16 * j + lr;
            const float cnj = cn_sh[kg_];
#pragma unroll
            for (int i = 0; i < 2; i++)
#pragma unroll
                for (int r = 0; r < 4; r++) {
                    const int s = 4 * i + r;
                    const float v = 2.0f * acc[i][j][r] - xn_sh[wrow + 16 * i + 4 * lg + r] - cnj;
                    if (v > v1[s])       { v2[s] = v1[s]; v1[s] = v; i1[s] = kg_; }
                    else if (v > v2[s])  { v2[s] = v; }
                    else if (v == v1[s]) { v2[s] = v; }  // exact tie -> margin 0
                }
        }
    }

    // merge across the 16 col-lanes (lane&15) per row slot, then decide
#pragma unroll
    for (int i = 0; i < 2; i++)
#pragma unroll
        for (int r = 0; r < 4; r++) {
            const int s = 4 * i + r;
            float a1v = v1[s], a2v = v2[s];
            int   ai  = i1[s];
#pragma unroll
            for (int m = 1; m <= 8; m <<= 1) {
                const float ov1 = __shfl_xor(a1v, m);
                const int   oi  = __shfl_xor(ai, m);
                const float ov2 = __shfl_xor(a2v, m);
                if (ov1 > a1v)      { a2v = fmaxf(a1v, ov2); a1v = ov1; ai = oi; }
                else if (ov1 < a1v) { a2v = fmaxf(a2v, ov1); }
                else                { ai = min(ai, oi); a2v = a1v; }
            }
            if (lr == 0) {
                const int row = wrow + 16 * i + 4 * lg + r;
                const int ok = (a1v - a2v >= EPS) ? 1 : 0;
                rbi[row] = ai;
                rok[row] = ok;
                if (!ok) { const int pos = atomicAdd(cnt, 1); list[pos] = n0 + row; }
            }
        }
    __syncthreads();   // drains pad-stage DMA too

    if (t < TM && rok[t]) {
        const int row = n0 + t;
        const int bi  = rbi[t];
        const float dot = np_dot256(x + (size_t)row * D, c + (size_t)bi * D);
        const float v = __fsub_rn(__fsub_rn(__fmul_rn(2.0f, dot), xn_sh[t]), cn[bi]);
        out[row]     = v;
        out[N + row] = (float)bi;
    }
}

__global__ __launch_bounds__(256) void fallback_kernel(const float* __restrict__ x,
                                                       const float* __restrict__ c,
                                                       const float* __restrict__ cn,
                                                       float* __restrict__ out,
                                                       const int* __restrict__ cnt,
                                                       const int* __restrict__ list) {
    __shared__ float xrow[D];
    __shared__ float xn_s;
    __shared__ float wv[4];
    __shared__ int   wi[4];
    const int tid = threadIdx.x, lane = tid & 63, w = tid >> 6;
    const int total = *cnt;
    for (int idx = blockIdx.x; idx < total; idx += gridDim.x) {
        const int row = list[idx];
        if (tid < 64) *(float4*)&xrow[4 * tid] = ((const float4*)(x + (size_t)row * D))[tid];
        __syncthreads();
        if (tid == 0) xn_s = np_pw256_sq(xrow);
        __syncthreads();
        const float xn = xn_s;
        float bv = -__builtin_inff();
        int   bi = 0;
#pragma unroll
        for (int j = 0; j < 4; j++) {
            const int k = 4 * tid + j;  // ascending within thread
            const float dot = np_dot256(xrow, c + (size_t)k * D);
            const float v = __fsub_rn(__fsub_rn(__fmul_rn(2.0f, dot), xn), cn[k]);
            if (v > bv) { bv = v; bi = k; }
        }
#pragma unroll
        for (int m = 1; m <= 32; m <<= 1) {
            const float ov = __shfl_xor(bv, m);
            const int   oi = __shfl_xor(bi, m);
            if (ov > bv || (ov == bv && oi < bi)) { bv = ov; bi = oi; }
        }
        if (lane == 0) { wv[w] = bv; wi[w] = bi; }
        __syncthreads();
        if (tid == 0) {
#pragma unroll
            for (int ww = 1; ww < 4; ww++) {
                if (wv[ww] > bv || (wv[ww] == bv && wi[ww] < bi)) { bv = wv[ww]; bi = wi[ww]; }
            }
            out[row]     = bv;
            out[N + row] = (float)bi;
        }
        __syncthreads();
    }
}

extern "C" void kernel_launch(void* const* d_in, const int* in_sizes, int n_in,
                              void* d_out, int out_size, void* d_ws, size_t ws_size,
                              hipStream_t stream) {
    const float* x = (const float*)d_in[0];
    const float* c = (const float*)d_in[1];
    float* out     = (float*)d_out;
    // ws layout: [0,4096) cn | [4096,4100) count | [4608, ...) flagged-row list
    float* cn = (float*)d_ws;
    int* cnt  = (int*)((char*)d_ws + 4096);
    int* list = (int*)((char*)d_ws + 4608);

    hipMemsetAsync(cnt, 0, sizeof(int), stream);
    prep_kernel<<<128, 256, 0, stream>>>(c, cn);
    fast_kernel<<<N / TM, 256, 0, stream>>>(x, c, cn, out, cnt, list);
    fallback_kernel<<<1024, 256, 0, stream>>>(x, c, cn, out, cnt, list);
}

// Round 8
// 534.710 us; speedup vs baseline: 1.0603x; 1.0603x over previous
//
#include <hip/hip_runtime.h>

// Nearest-centroid assignment. out[0..N) = max_sim (float), out[N..2N) = argmax (as float).
//
// Decision semantics = round-6 validated np bit-model (einsum baseline-SSE3 unfused
// cascade + AVX512F pairwise norms + fl32 chain + first-max). Fast path: f16x3-split
// MFMA GEMM (hi*hi + hi*lo + lo*hi, fp32 accum), |fast - np| ~ 1e-4 << EPS/2.
// v8: fit the 128-VGPR budget BY CONSTRUCTION. v3-v7 needed ~226 regs/lane; the
// allocator (occupancy target ignores LDS; launch_bounds min-only) stayed at 128 and
// REMATERIALIZED x-loads + hi/lo conversions into the kb-loop (evidence: VALUBusy 36%,
// +8.2MB scratch WRITE, +77MB FETCH). Now 8 waves x 16 rows (512 thr): A-frags 64
// VGPRs, acc 32, top-2 12 -> ~128 total. Conversion truly once; occupancy doubles
// (16 waves/CU). Quad-buffered B tiles, depth-2 prefetch (vmcnt(4): 2 loads/stage at
// 512 thr), one barrier/stage, per-block rotated schedule, setprio.
// Margin >= EPS -> winner provably = np winner, recompute np-bit-exactly;
// margin < EPS -> row -> fallback (full np-exact).
constexpr int N = 131072;
constexpr int D = 256;
constexpr int K = 1024;

constexpr int TM = 128;   // rows per block (8 waves x 16 rows)
constexpr int TK = 128;   // centroids per chunk
constexpr float EPS = 0.08f;

typedef _Float16 f16x8 __attribute__((ext_vector_type(8)));
typedef float f32x4 __attribute__((ext_vector_type(4)));

// c pre-split into fragment-tiled layout: [stage=kblk*8+dc][part][kg][krow][e]
// stage block = 8192 f16 (16 KiB); 64 real stages + 2 pad stages (uniform prefetch).
__device__ _Float16 g_ctile[66 * 8192];

__device__ __forceinline__ float sqf(float a) { return __fmul_rn(a, a); }

// numpy AVX512F pairwise base case over 128 contiguous squares.
__device__ __forceinline__ float np_sumsq128(const float* q) {
    float lane[16];
#pragma unroll
    for (int j = 0; j < 16; j++) {
        const float r0 = __fadd_rn(sqf(q[j]),      sqf(q[64 + j]));
        const float r1 = __fadd_rn(sqf(q[16 + j]), sqf(q[80 + j]));
        const float r2 = __fadd_rn(sqf(q[32 + j]), sqf(q[96 + j]));
        const float r3 = __fadd_rn(sqf(q[48 + j]), sqf(q[112 + j]));
        lane[j] = __fadd_rn(__fadd_rn(r0, r1), __fadd_rn(r2, r3));
    }
    float t[8];
#pragma unroll
    for (int i = 0; i < 8; i++) t[i] = __fadd_rn(lane[i], lane[i + 8]);
    float u[4];
#pragma unroll
    for (int i = 0; i < 4; i++) u[i] = __fadd_rn(t[i], t[i + 4]);
    return __fadd_rn(__fadd_rn(u[0], u[2]), __fadd_rn(u[1], u[3]));
}
__device__ __forceinline__ float np_pw256_sq(const float* p) {
    return __fadd_rn(np_sumsq128(p), np_sumsq128(p + 128));
}

// np einsum bit-exact dot over 256 contiguous floats.
__device__ __forceinline__ float np_dot256(const float* a, const float* b) {
    float A[4] = {0.f, 0.f, 0.f, 0.f};
#pragma unroll 4
    for (int t = 0; t < 16; t++) {
#pragma unroll
        for (int i = 3; i >= 0; i--) {
            const int base = 16 * t + 4 * i;
#pragma unroll
            for (int j = 0; j < 4; j++)
                A[j] = __fadd_rn(A[j], __fmul_rn(a[base + j], b[base + j]));
        }
    }
    return __fadd_rn(__fadd_rn(A[0], A[1]), __fadd_rn(A[2], A[3]));
}

// split one float component into (hi,lo) f16 pair at index idx of vectors he/le
#define SPL(vec, comp, he, le, idx)                                  \
    {                                                                \
        const float fv_ = (vec).comp;                                \
        const _Float16 hh_ = (_Float16)fv_;                          \
        he[idx] = hh_;                                               \
        le[idx] = (_Float16)(fv_ - (float)hh_);                      \
    }

// Pre-split c into g_ctile fragment-tiled layout; threads with idx<K also compute cn.
__global__ __launch_bounds__(256) void prep_kernel(const float* __restrict__ c,
                                                   float* __restrict__ cn) {
    const int idx = blockIdx.x * 256 + threadIdx.x;   // [0, 32768)
    const int kglob = idx >> 5;                        // centroid row
    const int dslot = idx & 31;                        // dc*4 + kg
    const int dc = dslot >> 2, kg = dslot & 3;
    const float* src = c + (size_t)kglob * D + dc * 32 + kg * 8;
    const float4 s0 = ((const float4*)src)[0];
    const float4 s1 = ((const float4*)src)[1];
    f16x8 h, l;
    SPL(s0, x, h, l, 0) SPL(s0, y, h, l, 1) SPL(s0, z, h, l, 2) SPL(s0, w, h, l, 3)
    SPL(s1, x, h, l, 4) SPL(s1, y, h, l, 5) SPL(s1, z, h, l, 6) SPL(s1, w, h, l, 7)
    const int kblk = kglob >> 7, krow = kglob & 127;
    const int st = kblk * 8 + dc;
    _Float16* base = g_ctile + (size_t)st * 8192;
    *(f16x8*)&base[kg * 1024 + krow * 8]        = h;
    *(f16x8*)&base[4096 + kg * 1024 + krow * 8] = l;
    if (idx < K) cn[idx] = np_pw256_sq(c + (size_t)idx * D);
}

#define WAITVM(n) asm volatile("s_waitcnt vmcnt(" #n ")" ::: "memory")

__global__ __launch_bounds__(512, 4) void fast_kernel(const float* __restrict__ x,
                                                      const float* __restrict__ c,
                                                      const float* __restrict__ cn,
                                                      float* __restrict__ out,
                                                      int* __restrict__ cnt,
                                                      int* __restrict__ list) {
    __shared__ _Float16 cs[4][8192] __attribute__((aligned(16)));  // quad-buffered B tile
    __shared__ float cn_sh[K];
    __shared__ float xn_sh[TM];
    __shared__ int   rbi[TM];
    __shared__ int   rok[TM];

    const int t    = threadIdx.x;
    const int n0   = blockIdx.x * TM;
    const int lane = t & 63;
    const int w    = t >> 6;        // wave id 0..7
    const int wrow = w * 16;        // wave owns rows [wrow, wrow+16)
    const int lr   = lane & 15;     // fragment row/col coordinate
    const int lg   = lane >> 4;     // fragment k-group / C row-group

    // per-block schedule rotation (spreads g_ctile reads across stage windows)
    const int kbR = blockIdx.x & 7;
    const int dcR = (blockIdx.x >> 3) & 7;
    // physical stage for linear exec position p (p in [0,64); >=64 -> pad stage)
#define PHYS(p_) ((p_) < 64 ? (((((p_) >> 3) + kbR) & 7) << 3) | ((((p_) & 7) + dcR) & 7) : (p_))

    // 512 threads x 2 loads x 16 B = 16 KiB = one stage
#define STAGE(buf_, sidx_)                                                          \
    {                                                                               \
        const _Float16* gp_ = g_ctile + (size_t)(sidx_) * 8192 + t * 8;             \
        _Float16* lp_ = &cs[buf_][t * 8];                                           \
        __builtin_amdgcn_global_load_lds(                                           \
            (const __attribute__((address_space(1))) void*)gp_,                     \
            (__attribute__((address_space(3))) void*)lp_, 16, 0, 0);                \
        __builtin_amdgcn_global_load_lds(                                           \
            (const __attribute__((address_space(1))) void*)(gp_ + 4096),            \
            (__attribute__((address_space(3))) void*)(lp_ + 4096), 16, 0, 0);       \
    }

    // issue first two stages (rotated), then overlap prologue work with the DMA
    STAGE(0, PHYS(0));
    STAGE(1, PHYS(1));

#pragma unroll
    for (int q = 0; q < 2; q++) cn_sh[t + 512 * q] = cn[t + 512 * q];
    if (t < TM) xn_sh[t] = np_pw256_sq(x + (size_t)(n0 + t) * D);

    // A fragments: load + hi/lo split ONCE into registers (64 VGPRs total), PRE-ROTATED
    // so execution index st (static) holds physical depth (st + dcR) & 7.
    // ah/al[st] covers row (wrow + lr), d = ((st+dcR)&7)*32 + lg*8 .. +8
    f16x8 ah[8], al[8];
#pragma unroll
    for (int st = 0; st < 8; st++) {
        const int pst = (st + dcR) & 7;   // physical depth stage
        const float* src = x + (size_t)(n0 + wrow + lr) * D + pst * 32 + lg * 8;
        const float4 s0 = ((const float4*)src)[0];
        const float4 s1 = ((const float4*)src)[1];
        f16x8 h, l;
        SPL(s0, x, h, l, 0) SPL(s0, y, h, l, 1) SPL(s0, z, h, l, 2) SPL(s0, w, h, l, 3)
        SPL(s1, x, h, l, 4) SPL(s1, y, h, l, 5) SPL(s1, z, h, l, 6) SPL(s1, w, h, l, 7)
        ah[st] = h; al[st] = l;
    }

    float v1[4], v2[4];
    int   i1[4];
#pragma unroll
    for (int s = 0; s < 4; s++) {
        v1[s] = -__builtin_inff(); v2[s] = -__builtin_inff(); i1[s] = 0;
    }

    __syncthreads();   // xn/cn visible; also drains stages 0,1 (vmcnt 0)

    for (int kb0 = 0; kb0 < 8; kb0++) {
        const int kbE = (kb0 + kbR) & 7;   // physical kb chunk this iteration computes
        f32x4 acc[8];
#pragma unroll
        for (int j = 0; j < 8; j++) acc[j] = (f32x4)(0.f);

#pragma unroll
        for (int dc8 = 0; dc8 < 8; dc8++) {
            // linear exec position p = kb0*8 + dc8; buffer ids p&3 == dc8&3 (static)
            const int p2 = kb0 * 8 + dc8 + 2;
            STAGE((dc8 + 2) & 3, PHYS(p2));       // pad stages 64,65 land in dead buffers
            WAITVM(4);                            // own loads of stage p complete
            __builtin_amdgcn_s_barrier();         // all waves' portions of stage p in LDS
            __builtin_amdgcn_sched_barrier(0);    // no ds_read hoisting above barrier
            asm volatile("" ::: "memory");

            const _Float16* csb = &cs[dc8 & 3][0];
            __builtin_amdgcn_s_setprio(1);
#pragma unroll
            for (int j = 0; j < 8; j++) {
                const f16x8 bh = *(const f16x8*)&csb[lg * 1024 + (16 * j + lr) * 8];
                const f16x8 bl = *(const f16x8*)&csb[4096 + lg * 1024 + (16 * j + lr) * 8];
                acc[j] = __builtin_amdgcn_mfma_f32_16x16x32_f16(ah[dc8], bh, acc[j], 0, 0, 0);
                acc[j] = __builtin_amdgcn_mfma_f32_16x16x32_f16(al[dc8], bh, acc[j], 0, 0, 0);
                acc[j] = __builtin_amdgcn_mfma_f32_16x16x32_f16(ah[dc8], bl, acc[j], 0, 0, 0);
            }
            __builtin_amdgcn_s_setprio(0);
            asm volatile("" ::: "memory");
            // no trailing barrier: 4-buffer rotation keeps issue(p+2) != any live read buffer
        }

        // chunk epilogue: C/D layout col = lane&15, row = 4*(lane>>4)+reg (m89-verified).
        // kg ascending within lane (j ascending); first-max kept via strict >.
        // (kb rotation is safe: distinct values are order-independent; exact ties
        //  force margin 0 -> fallback, so tie-index order never reaches the output.)
#pragma unroll
        for (int j = 0; j < 8; j++) {
            const int kg_ = kbE * TK + 16 * j + lr;
            const float cnj = cn_sh[kg_];
#pragma unroll
            for (int r = 0; r < 4; r++) {
                const float v = 2.0f * acc[j][r] - xn_sh[wrow + 4 * lg + r] - cnj;
                if (v > v1[r])       { v2[r] = v1[r]; v1[r] = v; i1[r] = kg_; }
                else if (v > v2[r])  { v2[r] = v; }
                else if (v == v1[r]) { v2[r] = v; }  // exact tie -> margin 0
            }
        }
    }

    // merge across the 16 col-lanes (lane&15) per row slot, then decide
#pragma unroll
    for (int r = 0; r < 4; r++) {
        float a1v = v1[r], a2v = v2[r];
        int   ai  = i1[r];
#pragma unroll
        for (int m = 1; m <= 8; m <<= 1) {
            const float ov1 = __shfl_xor(a1v, m);
            const int   oi  = __shfl_xor(ai, m);
            const float ov2 = __shfl_xor(a2v, m);
            if (ov1 > a1v)      { a2v = fmaxf(a1v, ov2); a1v = ov1; ai = oi; }
            else if (ov1 < a1v) { a2v = fmaxf(a2v, ov1); }
            else                { ai = min(ai, oi); a2v = a1v; }
        }
        if (lr == 0) {
            const int row = wrow + 4 * lg + r;
            const int ok = (a1v - a2v >= EPS) ? 1 : 0;
            rbi[row] = ai;
            rok[row] = ok;
            if (!ok) { const int pos = atomicAdd(cnt, 1); list[pos] = n0 + row; }
        }
    }
    __syncthreads();   // drains pad-stage DMA too

    if (t < TM && rok[t]) {
        const int row = n0 + t;
        const int bi  = rbi[t];
        const float dot = np_dot256(x + (size_t)row * D, c + (size_t)bi * D);
        const float v = __fsub_rn(__fsub_rn(__fmul_rn(2.0f, dot), xn_sh[t]), cn[bi]);
        out[row]     = v;
        out[N + row] = (float)bi;
    }
}

__global__ __launch_bounds__(256) void fallback_kernel(const float* __restrict__ x,
                                                       const float* __restrict__ c,
                                                       const float* __restrict__ cn,
                                                       float* __restrict__ out,
                                                       const int* __restrict__ cnt,
                                                       const int* __restrict__ list) {
    __shared__ float xrow[D];
    __shared__ float xn_s;
    __shared__ float wv[4];
    __shared__ int   wi[4];
    const int tid = threadIdx.x, lane = tid & 63, w = tid >> 6;
    const int total = *cnt;
    for (int idx = blockIdx.x; idx < total; idx += gridDim.x) {
        const int row = list[idx];
        if (tid < 64) *(float4*)&xrow[4 * tid] = ((const float4*)(x + (size_t)row * D))[tid];
        __syncthreads();
        if (tid == 0) xn_s = np_pw256_sq(xrow);
        __syncthreads();
        const float xn = xn_s;
        float bv = -__builtin_inff();
        int   bi = 0;
#pragma unroll
        for (int j = 0; j < 4; j++) {
            const int k = 4 * tid + j;  // ascending within thread
            const float dot = np_dot256(xrow, c + (size_t)k * D);
            const float v = __fsub_rn(__fsub_rn(__fmul_rn(2.0f, dot), xn), cn[k]);
            if (v > bv) { bv = v; bi = k; }
        }
#pragma unroll
        for (int m = 1; m <= 32; m <<= 1) {
            const float ov = __shfl_xor(bv, m);
            const int   oi = __shfl_xor(bi, m);
            if (ov > bv || (ov == bv && oi < bi)) { bv = ov; bi = oi; }
        }
        if (lane == 0) { wv[w] = bv; wi[w] = bi; }
        __syncthreads();
        if (tid == 0) {
#pragma unroll
            for (int ww = 1; ww < 4; ww++) {
                if (wv[ww] > bv || (wv[ww] == bv && wi[ww] < bi)) { bv = wv[ww]; bi = wi[ww]; }
            }
            out[row]     = bv;
            out[N + row] = (float)bi;
        }
        __syncthreads();
    }
}

extern "C" void kernel_launch(void* const* d_in, const int* in_sizes, int n_in,
                              void* d_out, int out_size, void* d_ws, size_t ws_size,
                              hipStream_t stream) {
    const float* x = (const float*)d_in[0];
    const float* c = (const float*)d_in[1];
    float* out     = (float*)d_out;
    // ws layout: [0,4096) cn | [4096,4100) count | [4608, ...) flagged-row list
    float* cn = (float*)d_ws;
    int* cnt  = (int*)((char*)d_ws + 4096);
    int* list = (int*)((char*)d_ws + 4608);

    hipMemsetAsync(cnt, 0, sizeof(int), stream);
    prep_kernel<<<128, 256, 0, stream>>>(c, cn);
    fast_kernel<<<N / TM, 512, 0, stream>>>(x, c, cn, out, cnt, list);
    fallback_kernel<<<1024, 256, 0, stream>>>(x, c, cn, out, cnt, list);
}